// Round 1
// baseline (1231.065 us; speedup 1.0000x reference)
//
#include <hip/hip_runtime.h>
#include <stdint.h>

typedef unsigned short u16;
typedef __attribute__((ext_vector_type(8))) short  s16x8;
typedef __attribute__((ext_vector_type(8))) __bf16 b16x8;
typedef __attribute__((ext_vector_type(4))) float  f32x4;

__device__ __forceinline__ float bf2f(u16 u){
  union { unsigned int ui; float f; } v; v.ui = ((unsigned int)u) << 16; return v.f;
}
__device__ __forceinline__ u16 f2bf(float f){
  union { float f; unsigned int ui; } v; v.f = f;
  unsigned int u = v.ui;
  u += 0x7FFFu + ((u >> 16) & 1u);      // RNE
  return (u16)(u >> 16);
}
__device__ __forceinline__ f32x4 mfma16(s16x8 a, s16x8 b, f32x4 c){
  return __builtin_amdgcn_mfma_f32_16x16x32_bf16(
      __builtin_bit_cast(b16x8, a), __builtin_bit_cast(b16x8, b), c, 0, 0, 0);
}

// ---------------- elementwise cast f32 -> bf16 (8 elems/thread) ----------------
__global__ __launch_bounds__(256) void cast_f32_bf16(const float* __restrict__ in,
                                                     u16* __restrict__ out, int n8){
  int i = blockIdx.x * 256 + threadIdx.x;
  if (i >= n8) return;
  const f32x4* p = (const f32x4*)(in + (size_t)i * 8);
  f32x4 a = p[0], c = p[1];
  s16x8 o;
#pragma unroll
  for (int j = 0; j < 4; j++){ o[j] = (short)f2bf(a[j]); o[j+4] = (short)f2bf(c[j]); }
  *(s16x8*)(out + (size_t)i * 8) = o;
}

// ---------------- transpose + cast: in f32 [R][C] -> out bf16 [C][R] ----------------
__global__ __launch_bounds__(256) void tcast(const float* __restrict__ in,
                                             u16* __restrict__ out, int R, int C){
  __shared__ float tile[32][33];
  int c0 = blockIdx.x * 32, r0 = blockIdx.y * 32;
  int tc = threadIdx.x & 31, tr = threadIdx.x >> 5;       // tr in 0..7
#pragma unroll
  for (int p = 0; p < 4; p++)
    tile[tr + 8*p][tc] = in[(size_t)(r0 + tr + 8*p) * C + c0 + tc];
  __syncthreads();
  int rr = threadIdx.x & 31, cc = threadIdx.x >> 5;
#pragma unroll
  for (int p = 0; p < 4; p++)
    out[(size_t)(c0 + cc + 8*p) * R + r0 + rr] = f2bf(tile[rr][cc + 8*p]);
}

// ---------------- GEMM: C[M,N] = A[M,K=1024] * Bt[N,K=1024]^T (bf16 MFMA) ----------------
// mode 0: epilogue routes n<1024 -> Q, <2048 -> K, else V   (layout [b][h][i][64] bf16)
// mode 1: epilogue adds b_r and writes R [h][i][64] bf16
__global__ __launch_bounds__(256) void gemm_bt(const u16* __restrict__ A,
                                               const u16* __restrict__ Bt,
                                               int mode,
                                               u16* __restrict__ Qo, u16* __restrict__ Ko,
                                               u16* __restrict__ Vo, u16* __restrict__ Ro,
                                               const float* __restrict__ brp){
  __shared__ __align__(16) u16 lsA[2][128 * 32];
  __shared__ __align__(16) u16 lsB[2][128 * 32];
  int m0 = blockIdx.y * 128, n0 = blockIdx.x * 128;
  int t = threadIdx.x, wid = t >> 6, lane = t & 63;
  int lrow = lane & 15, lk = lane >> 4;
  int wr = wid >> 1, wc = wid & 1;

  f32x4 acc[4][4];
#pragma unroll
  for (int i = 0; i < 4; i++)
#pragma unroll
    for (int j = 0; j < 4; j++) acc[i][j] = (f32x4){0.f, 0.f, 0.f, 0.f};

  const u16* Ab = A  + (size_t)m0 * 1024;
  const u16* Bb = Bt + (size_t)n0 * 1024;

  s16x8 ra[2], rb[2];
#pragma unroll
  for (int p = 0; p < 2; p++){
    int c = p * 256 + t;
    ra[p] = *(const s16x8*)(Ab + (size_t)(c >> 2) * 1024 + (c & 3) * 8);
    rb[p] = *(const s16x8*)(Bb + (size_t)(c >> 2) * 1024 + (c & 3) * 8);
  }

  for (int kt = 0; kt < 32; kt++){
    int buf = kt & 1;
#pragma unroll
    for (int p = 0; p < 2; p++){
      int c = p * 256 + t;
      *(s16x8*)(lsA[buf] + (size_t)c * 8) = ra[p];
      *(s16x8*)(lsB[buf] + (size_t)c * 8) = rb[p];
    }
    __syncthreads();
    if (kt < 31){
      int k0 = (kt + 1) * 32;
#pragma unroll
      for (int p = 0; p < 2; p++){
        int c = p * 256 + t;
        ra[p] = *(const s16x8*)(Ab + (size_t)(c >> 2) * 1024 + k0 + (c & 3) * 8);
        rb[p] = *(const s16x8*)(Bb + (size_t)(c >> 2) * 1024 + k0 + (c & 3) * 8);
      }
    }
    s16x8 af[4], bfr[4];
#pragma unroll
    for (int i = 0; i < 4; i++)
      af[i] = *(const s16x8*)(lsA[buf] + (wr * 64 + i * 16 + lrow) * 32 + lk * 8);
#pragma unroll
    for (int j = 0; j < 4; j++)
      bfr[j] = *(const s16x8*)(lsB[buf] + (wc * 64 + j * 16 + lrow) * 32 + lk * 8);
#pragma unroll
    for (int i = 0; i < 4; i++)
#pragma unroll
      for (int j = 0; j < 4; j++)
        acc[i][j] = mfma16(af[i], bfr[j], acc[i][j]);
    __syncthreads();
  }

  // epilogue: C row = m0+wr*64+i*16+4*lk+r ; col = n0+wc*64+j*16+lrow
#pragma unroll
  for (int i = 0; i < 4; i++)
#pragma unroll
    for (int j = 0; j < 4; j++){
      int mbase = m0 + wr * 64 + i * 16 + lk * 4;
      int ncol  = n0 + wc * 64 + j * 16 + lrow;
#pragma unroll
      for (int r = 0; r < 4; r++){
        int m = mbase + r;
        float val = acc[i][j][r];
        if (mode == 0){
          int sel = ncol >> 10;
          int hd = ncol & 1023;
          int h = hd >> 6, dh = hd & 63;
          int b = m & 3, iq = m >> 2;
          size_t o = ((size_t)(b * 16 + h) * 2048 + iq) * 64 + dh;
          u16 vb = f2bf(val);
          if (sel == 0) Qo[o] = vb; else if (sel == 1) Ko[o] = vb; else Vo[o] = vb;
        } else {
          int h = ncol >> 6, dh = ncol & 63;
          Ro[((size_t)h * 2048 + m) * 64 + dh] = f2bf(val + brp[ncol]);
        }
      }
    }
}

// ---------------- V [bh][2048][64] -> VT [bh][64][2048] (bf16) ----------------
__global__ __launch_bounds__(256) void transpose_v(const u16* __restrict__ V,
                                                   u16* __restrict__ VT){
  __shared__ u16 tile[64][65];
  int bh = blockIdx.y, i0 = blockIdx.x * 64;
  const u16* src = V + ((size_t)bh * 2048 + i0) * 64;
  int t = threadIdx.x;
#pragma unroll
  for (int p = 0; p < 2; p++){
    int idx = (p * 256 + t) * 8;
    int row = idx >> 6, col = idx & 63;
    s16x8 v = *(const s16x8*)(src + idx);
#pragma unroll
    for (int e = 0; e < 8; e++) tile[row][col + e] = (u16)v[e];
  }
  __syncthreads();
  u16* dst = VT + (size_t)bh * 64 * 2048 + i0;
#pragma unroll
  for (int p = 0; p < 2; p++){
    int idx = (p * 256 + t) * 8;
    int dh = idx >> 6, ii = idx & 63;
    s16x8 o;
#pragma unroll
    for (int e = 0; e < 8; e++) o[e] = (short)tile[ii + e][dh];
    *(s16x8*)(dst + (size_t)dh * 2048 + ii) = o;
  }
}

// ---------------- fused rel-shift flash attention ----------------
// grid (32 qtiles, 16 h, 4 b), 256 threads = 4 waves, wave = 16 q rows.
// BDs[q,k]: k<=q -> qb[q]·r[k-q+2047]; k==q+1 -> 0; k>q+1 -> qb[q+1]·r[k-q-2]
__global__ __launch_bounds__(256) void attn_kernel(const u16* __restrict__ Qm,
                                                   const u16* __restrict__ Km,
                                                   const u16* __restrict__ Vt,
                                                   const u16* __restrict__ Rm,
                                                   const float* __restrict__ bq,
                                                   const float* __restrict__ bk,
                                                   float* __restrict__ Out){
  __shared__ __align__(16) float G1s[4][48 * 16];
  __shared__ __align__(16) float G2s[4][48 * 16];
  __shared__ __align__(16) u16   Ps [4][16 * 32];
  int b = blockIdx.z, h = blockIdx.y;
  int wid = threadIdx.x >> 6, lane = threadIdx.x & 63;
  int lrow = lane & 15, lk = lane >> 4;
  int q0 = blockIdx.x * 64 + wid * 16;
  const size_t bh = (size_t)b * 16 + h;
  const u16* Qp = Qm + bh * 2048 * 64;
  const u16* Kp = Km + bh * 2048 * 64;
  const u16* Vp = Vt + bh * 64 * 2048;
  const u16* Rp = Rm + (size_t)h * 2048 * 64;
  float* G1w = G1s[wid];
  float* G2w = G2s[wid];
  u16*   Pw  = Ps[wid];

  // q fragments (A-layout: lane holds row lane&15, k = (lane>>4)*8+j)
  s16x8 qa[2], qb0[2], qb1[2];
  {
    const float* bqp = bq + h * 64;
    const float* bkp = bk + h * 64;
    int r1 = q0 + lrow + 1; if (r1 > 2047) r1 = 2047;   // row 2048 never selected
#pragma unroll
    for (int d = 0; d < 2; d++){
      int doff = d * 32 + lk * 8;
      s16x8 raw  = *(const s16x8*)(Qp + (size_t)(q0 + lrow) * 64 + doff);
      s16x8 raw1 = *(const s16x8*)(Qp + (size_t)r1 * 64 + doff);
      s16x8 a, c0, c1;
#pragma unroll
      for (int j = 0; j < 8; j++){
        float qv  = bf2f((u16)raw[j]);
        float q1v = bf2f((u16)raw1[j]);
        a[j]  = (short)f2bf(qv  + bqp[doff + j]);
        c0[j] = (short)f2bf(qv  + bkp[doff + j]);
        c1[j] = (short)f2bf(q1v + bkp[doff + j]);
      }
      qa[d] = a; qb0[d] = c0; qb1[d] = c1;
    }
  }

  float m_r[4], l_r[4];
  f32x4 Oc[4];
#pragma unroll
  for (int r = 0; r < 4; r++){ m_r[r] = -3e38f; l_r[r] = 0.f; }
#pragma unroll
  for (int f = 0; f < 4; f++) Oc[f] = (f32x4){0.f, 0.f, 0.f, 0.f};

  for (int k0 = 0; k0 < 2048; k0 += 32){
    // ---- AC scores (2 col-frags x 2 d-halves)
    f32x4 S[2];
#pragma unroll
    for (int cf = 0; cf < 2; cf++){
      f32x4 acc = (f32x4){0.f, 0.f, 0.f, 0.f};
#pragma unroll
      for (int d = 0; d < 2; d++){
        s16x8 kf = *(const s16x8*)(Kp + (size_t)(k0 + cf * 16 + lrow) * 64 + d * 32 + lk * 8);
        acc = mfma16(qa[d], kf, acc);
      }
      S[cf] = acc;
    }
    // ---- BD windows: G[crow][w] over 48-wide r-row window
    int d0  = k0 - q0;
    bool need1 = (d0 <= 15);
    bool need2 = (d0 >= -29);
    int p1b = d0 + 2032;                 // k0 - (q0+15) + 2047
    if (need1){
#pragma unroll
      for (int wf = 0; wf < 3; wf++){
        f32x4 g = (f32x4){0.f, 0.f, 0.f, 0.f};
        int pr = p1b + wf * 16 + lrow;
        pr = pr < 0 ? 0 : (pr > 2047 ? 2047 : pr);
#pragma unroll
        for (int d = 0; d < 2; d++){
          s16x8 rf = *(const s16x8*)(Rp + (size_t)pr * 64 + d * 32 + lk * 8);
          g = mfma16(qb0[d], rf, g);
        }
        *(f32x4*)(G1w + (wf * 16 + lrow) * 16 + lk * 4) = g;   // [w][crow]
      }
    }
    if (need2){
      int p2b = p1b - 2049;
#pragma unroll
      for (int wf = 0; wf < 3; wf++){
        f32x4 g = (f32x4){0.f, 0.f, 0.f, 0.f};
        int pr = p2b + wf * 16 + lrow;
        pr = pr < 0 ? 0 : (pr > 2047 ? 2047 : pr);
#pragma unroll
        for (int d = 0; d < 2; d++){
          s16x8 rf = *(const s16x8*)(Rp + (size_t)pr * 64 + d * 32 + lk * 8);
          g = mfma16(qb1[d], rf, g);
        }
        *(f32x4*)(G2w + (wf * 16 + lrow) * 16 + lk * 4) = g;
      }
    }
    // ---- combine + online softmax (per-lane rows crow = 4*lk + r, col = lrow)
    float p_v[2][4];
#pragma unroll
    for (int r = 0; r < 4; r++){
      int crow = lk * 4 + r;
      float s2[2];
#pragma unroll
      for (int cf = 0; cf < 2; cf++){
        int delta = d0 + cf * 16 + lrow - crow;
        int w = cf * 16 + lrow - crow + 15;          // 0..46
        float bd;
        if (delta <= 0)      bd = G1w[w * 16 + crow];
        else if (delta == 1) bd = 0.f;
        else                 bd = G2w[w * 16 + crow];
        s2[cf] = (S[cf][r] + bd) * 0.125f;
      }
      float tm = fmaxf(s2[0], s2[1]);
#pragma unroll
      for (int mk = 1; mk < 16; mk <<= 1) tm = fmaxf(tm, __shfl_xor(tm, mk, 64));
      float mn = fmaxf(m_r[r], tm);
      float al = __expf(m_r[r] - mn);
      float p0 = __expf(s2[0] - mn);
      float p1 = __expf(s2[1] - mn);
      float sm = p0 + p1;
#pragma unroll
      for (int mk = 1; mk < 16; mk <<= 1) sm += __shfl_xor(sm, mk, 64);
      l_r[r] = l_r[r] * al + sm;
      m_r[r] = mn;
#pragma unroll
      for (int f = 0; f < 4; f++) Oc[f][r] *= al;
      p_v[0][r] = p0; p_v[1][r] = p1;
    }
    // ---- P to LDS [row][col], then PV
#pragma unroll
    for (int r = 0; r < 4; r++){
      int crow = lk * 4 + r;
      Pw[crow * 32 + lrow]      = f2bf(p_v[0][r]);
      Pw[crow * 32 + 16 + lrow] = f2bf(p_v[1][r]);
    }
    s16x8 pa = *(const s16x8*)(Pw + lrow * 32 + lk * 8);
#pragma unroll
    for (int f = 0; f < 4; f++){
      s16x8 vf = *(const s16x8*)(Vp + (size_t)(f * 16 + lrow) * 2048 + k0 + lk * 8);
      Oc[f] = mfma16(pa, vf, Oc[f]);
    }
  }
  // ---- epilogue: out[i][b][h*64+dh]
#pragma unroll
  for (int f = 0; f < 4; f++){
    int dh = f * 16 + lrow;
#pragma unroll
    for (int r = 0; r < 4; r++){
      int q = q0 + lk * 4 + r;
      Out[(size_t)q * 4096 + b * 1024 + h * 64 + dh] = Oc[f][r] / l_r[r];
    }
  }
}

extern "C" void kernel_launch(void* const* d_in, const int* in_sizes, int n_in,
                              void* d_out, int out_size, void* d_ws, size_t ws_size,
                              hipStream_t stream){
  const float* word = (const float*)d_in[0];   // [2048][4][1024]
  const float* pos  = (const float*)d_in[1];   // [2048][1024]
  const float* bq   = (const float*)d_in[2];   // [16][64]
  const float* bk   = (const float*)d_in[3];   // [16][64]
  const float* Wqkv = (const float*)d_in[4];   // [1024][3072]
  const float* Wr   = (const float*)d_in[5];   // [1024][1024]
  const float* br   = (const float*)d_in[6];   // [1024]
  float* out = (float*)d_out;

  char* ws = (char*)d_ws;
  size_t off = 0;
  u16* Abf   = (u16*)(ws + off); off += (size_t)8192 * 1024 * 2;   // word bf16 [8192][1024]
  u16* WqkvT = (u16*)(ws + off); off += (size_t)3072 * 1024 * 2;   // [3072][1024]
  u16* Pbf   = (u16*)(ws + off); off += (size_t)2048 * 1024 * 2;   // pos bf16
  u16* WrT   = (u16*)(ws + off); off += (size_t)1024 * 1024 * 2;   // [1024][1024]
  u16* Qb    = (u16*)(ws + off); off += (size_t)64 * 2048 * 64 * 2; // [b*h][i][64]
  u16* Kb    = (u16*)(ws + off); off += (size_t)64 * 2048 * 64 * 2;
  u16* Vb    = (u16*)(ws + off); off += (size_t)64 * 2048 * 64 * 2;
  u16* VTb   = (u16*)(ws + off); off += (size_t)64 * 64 * 2048 * 2; // [b*h][64][2048]
  u16* Rb    = (u16*)(ws + off); off += (size_t)16 * 2048 * 64 * 2; // [h][i][64]
  if (ws_size < off) return;  // insufficient scratch; leave output poisoned as signal

  cast_f32_bf16<<<4096, 256, 0, stream>>>(word, Abf, 1048576);
  cast_f32_bf16<<<1024, 256, 0, stream>>>(pos,  Pbf, 262144);
  tcast<<<dim3(96, 32), 256, 0, stream>>>(Wqkv, WqkvT, 1024, 3072);
  tcast<<<dim3(32, 32), 256, 0, stream>>>(Wr,   WrT,   1024, 1024);
  gemm_bt<<<dim3(24, 64), 256, 0, stream>>>(Abf, WqkvT, 0, Qb, Kb, Vb, nullptr, nullptr);
  gemm_bt<<<dim3(8, 16),  256, 0, stream>>>(Pbf, WrT,   1, nullptr, nullptr, nullptr, Rb, br);
  transpose_v<<<dim3(32, 64), 256, 0, stream>>>(Vb, VTb);
  attn_kernel<<<dim3(32, 16, 4), 256, 0, stream>>>(Qb, Kb, VTb, Rb, bq, bk, out);
}

// Round 2
// 989.456 us; speedup vs baseline: 1.2442x; 1.2442x over previous
//
#include <hip/hip_runtime.h>
#include <stdint.h>

typedef unsigned short u16;
typedef __attribute__((ext_vector_type(8))) short  s16x8;
typedef __attribute__((ext_vector_type(8))) __bf16 b16x8;
typedef __attribute__((ext_vector_type(4))) float  f32x4;

__device__ __forceinline__ float bf2f(u16 u){
  union { unsigned int ui; float f; } v; v.ui = ((unsigned int)u) << 16; return v.f;
}
__device__ __forceinline__ u16 f2bf(float f){
  union { float f; unsigned int ui; } v; v.f = f;
  unsigned int u = v.ui;
  u += 0x7FFFu + ((u >> 16) & 1u);      // RNE
  return (u16)(u >> 16);
}
__device__ __forceinline__ f32x4 mfma16(s16x8 a, s16x8 b, f32x4 c){
  return __builtin_amdgcn_mfma_f32_16x16x32_bf16(
      __builtin_bit_cast(b16x8, a), __builtin_bit_cast(b16x8, b), c, 0, 0, 0);
}

// ---------------- elementwise cast f32 -> bf16 (8 elems/thread) ----------------
__global__ __launch_bounds__(256) void cast_f32_bf16(const float* __restrict__ in,
                                                     u16* __restrict__ out, int n8){
  int i = blockIdx.x * 256 + threadIdx.x;
  if (i >= n8) return;
  const f32x4* p = (const f32x4*)(in + (size_t)i * 8);
  f32x4 a = p[0], c = p[1];
  s16x8 o;
#pragma unroll
  for (int j = 0; j < 4; j++){ o[j] = (short)f2bf(a[j]); o[j+4] = (short)f2bf(c[j]); }
  *(s16x8*)(out + (size_t)i * 8) = o;
}

// ---------------- transpose + cast: in f32 [R][C] -> out bf16 [C][R] ----------------
__global__ __launch_bounds__(256) void tcast(const float* __restrict__ in,
                                             u16* __restrict__ out, int R, int C){
  __shared__ float tile[32][33];
  int c0 = blockIdx.x * 32, r0 = blockIdx.y * 32;
  int tc = threadIdx.x & 31, tr = threadIdx.x >> 5;       // tr in 0..7
#pragma unroll
  for (int p = 0; p < 4; p++)
    tile[tr + 8*p][tc] = in[(size_t)(r0 + tr + 8*p) * C + c0 + tc];
  __syncthreads();
  int rr = threadIdx.x & 31, cc = threadIdx.x >> 5;
#pragma unroll
  for (int p = 0; p < 4; p++)
    out[(size_t)(c0 + cc + 8*p) * R + r0 + rr] = f2bf(tile[rr][cc + 8*p]);
}

// ---------------- GEMM: C[M,N] = A[M,K=1024] * Bt[N,K=1024]^T (bf16 MFMA) ----------------
__global__ __launch_bounds__(256) void gemm_bt(const u16* __restrict__ A,
                                               const u16* __restrict__ Bt,
                                               int mode,
                                               u16* __restrict__ Qo, u16* __restrict__ Ko,
                                               u16* __restrict__ Vo, u16* __restrict__ Ro,
                                               const float* __restrict__ brp){
  __shared__ __align__(16) u16 lsA[2][128 * 32];
  __shared__ __align__(16) u16 lsB[2][128 * 32];
  int m0 = blockIdx.y * 128, n0 = blockIdx.x * 128;
  int t = threadIdx.x, wid = t >> 6, lane = t & 63;
  int lrow = lane & 15, lk = lane >> 4;
  int wr = wid >> 1, wc = wid & 1;

  f32x4 acc[4][4];
#pragma unroll
  for (int i = 0; i < 4; i++)
#pragma unroll
    for (int j = 0; j < 4; j++) acc[i][j] = (f32x4){0.f, 0.f, 0.f, 0.f};

  const u16* Ab = A  + (size_t)m0 * 1024;
  const u16* Bb = Bt + (size_t)n0 * 1024;

  s16x8 ra[2], rb[2];
#pragma unroll
  for (int p = 0; p < 2; p++){
    int c = p * 256 + t;
    ra[p] = *(const s16x8*)(Ab + (size_t)(c >> 2) * 1024 + (c & 3) * 8);
    rb[p] = *(const s16x8*)(Bb + (size_t)(c >> 2) * 1024 + (c & 3) * 8);
  }

  for (int kt = 0; kt < 32; kt++){
    int buf = kt & 1;
#pragma unroll
    for (int p = 0; p < 2; p++){
      int c = p * 256 + t;
      *(s16x8*)(lsA[buf] + (size_t)c * 8) = ra[p];
      *(s16x8*)(lsB[buf] + (size_t)c * 8) = rb[p];
    }
    __syncthreads();
    if (kt < 31){
      int k0 = (kt + 1) * 32;
#pragma unroll
      for (int p = 0; p < 2; p++){
        int c = p * 256 + t;
        ra[p] = *(const s16x8*)(Ab + (size_t)(c >> 2) * 1024 + k0 + (c & 3) * 8);
        rb[p] = *(const s16x8*)(Bb + (size_t)(c >> 2) * 1024 + k0 + (c & 3) * 8);
      }
    }
    s16x8 af[4], bfr[4];
#pragma unroll
    for (int i = 0; i < 4; i++)
      af[i] = *(const s16x8*)(lsA[buf] + (wr * 64 + i * 16 + lrow) * 32 + lk * 8);
#pragma unroll
    for (int j = 0; j < 4; j++)
      bfr[j] = *(const s16x8*)(lsB[buf] + (wc * 64 + j * 16 + lrow) * 32 + lk * 8);
#pragma unroll
    for (int i = 0; i < 4; i++)
#pragma unroll
      for (int j = 0; j < 4; j++)
        acc[i][j] = mfma16(af[i], bfr[j], acc[i][j]);
    __syncthreads();
  }

#pragma unroll
  for (int i = 0; i < 4; i++)
#pragma unroll
    for (int j = 0; j < 4; j++){
      int mbase = m0 + wr * 64 + i * 16 + lk * 4;
      int ncol  = n0 + wc * 64 + j * 16 + lrow;
#pragma unroll
      for (int r = 0; r < 4; r++){
        int m = mbase + r;
        float val = acc[i][j][r];
        if (mode == 0){
          int sel = ncol >> 10;
          int hd = ncol & 1023;
          int h = hd >> 6, dh = hd & 63;
          int b = m & 3, iq = m >> 2;
          size_t o = ((size_t)(b * 16 + h) * 2048 + iq) * 64 + dh;
          u16 vb = f2bf(val);
          if (sel == 0) Qo[o] = vb; else if (sel == 1) Ko[o] = vb; else Vo[o] = vb;
        } else {
          int h = ncol >> 6, dh = ncol & 63;
          Ro[((size_t)h * 2048 + m) * 64 + dh] = f2bf(val + brp[ncol]);
        }
      }
    }
}

// ---------------- V [bh][2048][64] -> VT [bh][64][2048] (bf16) ----------------
__global__ __launch_bounds__(256) void transpose_v(const u16* __restrict__ V,
                                                   u16* __restrict__ VT){
  __shared__ u16 tile[64][65];
  int bh = blockIdx.y, i0 = blockIdx.x * 64;
  const u16* src = V + ((size_t)bh * 2048 + i0) * 64;
  int t = threadIdx.x;
#pragma unroll
  for (int p = 0; p < 2; p++){
    int idx = (p * 256 + t) * 8;
    int row = idx >> 6, col = idx & 63;
    s16x8 v = *(const s16x8*)(src + idx);
#pragma unroll
    for (int e = 0; e < 8; e++) tile[row][col + e] = (u16)v[e];
  }
  __syncthreads();
  u16* dst = VT + (size_t)bh * 64 * 2048 + i0;
#pragma unroll
  for (int p = 0; p < 2; p++){
    int idx = (p * 256 + t) * 8;
    int dh = idx >> 6, ii = idx & 63;
    s16x8 o;
#pragma unroll
    for (int e = 0; e < 8; e++) o[e] = (short)tile[ii + e][dh];
    *(s16x8*)(dst + (size_t)dh * 2048 + ii) = o;
  }
}

// ---------------- fused rel-shift flash attention, swapped (q lane-local) ----------------
// grid (32, 16, 4), 256 thr = 4 waves, wave = 16 q rows, KVBLK = 64.
// S^T = mfma(K, qa): D(k_local=4lk+r, q=lane&15). Softmax in-lane + 2 butterflies.
// BD: G^T = mfma(r_win, qb') -> LDS G[q][w] stride 84 (conflict-free), gather by w = klocal+15-lrow.
// BDs: d<=0 -> qb0·r[d+2047]; d==1 -> 0; d>=2 -> qb1·r[d-2]   (d = k - q)
__global__ __launch_bounds__(256) void attn2_kernel(const u16* __restrict__ Qm,
                                                    const u16* __restrict__ Km,
                                                    const u16* __restrict__ Vt,
                                                    const u16* __restrict__ Rm,
                                                    const float* __restrict__ bq,
                                                    const float* __restrict__ bk,
                                                    float* __restrict__ Out){
  __shared__ __align__(16) float Gs[4][16 * 84];
  __shared__ __align__(16) u16   Ps[4][16 * 88];
  const int b = blockIdx.z, h = blockIdx.y;
  const int wid = threadIdx.x >> 6, lane = threadIdx.x & 63;
  const int lrow = lane & 15, lk = lane >> 4;
  const int q0 = blockIdx.x * 64 + wid * 16;
  const size_t bh = (size_t)b * 16 + h;
  const u16* Qp = Qm + bh * 2048 * 64;
  const u16* Kp = Km + bh * 2048 * 64;
  const u16* Vp = Vt + bh * 64 * 2048;
  const u16* Rp = Rm + (size_t)h * 2048 * 64;
  float* Gw = Gs[wid];
  u16*   Pw = Ps[wid];

  // q fragments: frag[x=lane&15][dk=(lane>>4)*8+j]  (identical content serves A or B role)
  s16x8 qa[2], qb0[2], qb1[2];
  {
    const float* bqp = bq + h * 64;
    const float* bkp = bk + h * 64;
    int r1 = q0 + lrow + 1; if (r1 > 2047) r1 = 2047;   // q=2047's shifted row never selected
#pragma unroll
    for (int d = 0; d < 2; d++){
      int doff = d * 32 + lk * 8;
      s16x8 raw  = *(const s16x8*)(Qp + (size_t)(q0 + lrow) * 64 + doff);
      s16x8 raw1 = *(const s16x8*)(Qp + (size_t)r1 * 64 + doff);
      s16x8 a, c0, c1;
#pragma unroll
      for (int j = 0; j < 8; j++){
        float qv = bf2f((u16)raw[j]);
        float q1 = bf2f((u16)raw1[j]);
        a[j]  = (short)f2bf(qv + bqp[doff + j]);
        c0[j] = (short)f2bf(qv + bkp[doff + j]);
        c1[j] = (short)f2bf(q1 + bkp[doff + j]);
      }
      qa[d] = a; qb0[d] = c0; qb1[d] = c1;
    }
  }

  float m = -3.0e38f, l = 0.f;
  f32x4 Oc[4];
#pragma unroll
  for (int f = 0; f < 4; f++) Oc[f] = (f32x4){0.f, 0.f, 0.f, 0.f};

  const float cs = 0.125f * 1.44269504088896f;   // (1/sqrt(64)) * log2(e)

  for (int k0 = 0; k0 < 2048; k0 += 64){
    const int d0 = k0 - q0;
    // ---- S^T frags: A = K rows (k_local), B = qa
    f32x4 S[4];
#pragma unroll
    for (int kf = 0; kf < 4; kf++){
      f32x4 acc = (f32x4){0.f, 0.f, 0.f, 0.f};
#pragma unroll
      for (int d = 0; d < 2; d++){
        s16x8 kfr = *(const s16x8*)(Kp + (size_t)(k0 + kf * 16 + lrow) * 64 + d * 32 + lk * 8);
        acc = mfma16(kfr, qa[d], acc);
      }
      S[kf] = acc;
    }
    // ---- V prefetch (latency hidden under BD+softmax)
    s16x8 vreg[2][4];
#pragma unroll
    for (int ks = 0; ks < 2; ks++)
#pragma unroll
      for (int f = 0; f < 4; f++)
        vreg[ks][f] = *(const s16x8*)(Vp + (size_t)(f * 16 + lrow) * 2048 + k0 + ks * 32 + lk * 8);

    // ---- BD via shared window buffer (1-2 passes)
    float bd[4][4];
#pragma unroll
    for (int kf = 0; kf < 4; kf++)
#pragma unroll
      for (int r = 0; r < 4; r++) bd[kf][r] = 0.f;
    const int dlane = d0 + 4 * lk - lrow;       // delta for (kf=0, r=0)
    const int wbase = 15 - lrow + 4 * lk;       // w for (kf=0, r=0)

    if (d0 <= 15){                               // tile contains delta <= 0
      const int p1b = d0 + 2032;                 // r-idx = p1b + w = delta + 2047
#pragma unroll
      for (int wf = 0; wf < 5; wf++){
        int pr = p1b + wf * 16 + lrow;
        pr = pr < 0 ? 0 : (pr > 2047 ? 2047 : pr);
        f32x4 g = (f32x4){0.f, 0.f, 0.f, 0.f};
#pragma unroll
        for (int d = 0; d < 2; d++){
          s16x8 rf = *(const s16x8*)(Rp + (size_t)pr * 64 + d * 32 + lk * 8);
          g = mfma16(rf, qb0[d], g);
        }
        *(f32x4*)(Gw + lrow * 84 + wf * 16 + 4 * lk) = g;
      }
#pragma unroll
      for (int kf = 0; kf < 4; kf++){
        const float* gp = Gw + lrow * 84 + kf * 16 + wbase;
#pragma unroll
        for (int r = 0; r < 4; r++){
          float g = gp[r];
          bd[kf][r] = (dlane + kf * 16 + r <= 0) ? g : bd[kf][r];
        }
      }
    }
    if (d0 >= -61){                              // tile contains delta >= 2
      const int p2b = d0 - 17;                   // r-idx = p2b + w = delta - 2
#pragma unroll
      for (int wf = 0; wf < 5; wf++){
        int pr = p2b + wf * 16 + lrow;
        pr = pr < 0 ? 0 : (pr > 2047 ? 2047 : pr);
        f32x4 g = (f32x4){0.f, 0.f, 0.f, 0.f};
#pragma unroll
        for (int d = 0; d < 2; d++){
          s16x8 rf = *(const s16x8*)(Rp + (size_t)pr * 64 + d * 32 + lk * 8);
          g = mfma16(rf, qb1[d], g);
        }
        *(f32x4*)(Gw + lrow * 84 + wf * 16 + 4 * lk) = g;
      }
#pragma unroll
      for (int kf = 0; kf < 4; kf++){
        const float* gp = Gw + lrow * 84 + kf * 16 + wbase;
#pragma unroll
        for (int r = 0; r < 4; r++){
          float g = gp[r];
          bd[kf][r] = (dlane + kf * 16 + r >= 2) ? g : bd[kf][r];
        }
      }
    }
    // ---- softmax (q = lrow is lane-local; exp2 domain)
    float sv[4][4];
    float tmax = -3.0e38f;
#pragma unroll
    for (int kf = 0; kf < 4; kf++)
#pragma unroll
      for (int r = 0; r < 4; r++){
        float s = (S[kf][r] + bd[kf][r]) * cs;
        sv[kf][r] = s;
        tmax = fmaxf(tmax, s);
      }
    tmax = fmaxf(tmax, __shfl_xor(tmax, 16, 64));
    tmax = fmaxf(tmax, __shfl_xor(tmax, 32, 64));
    if (tmax > m + 11.5f){                       // defer-max: skip rescale for small growth
      float al = exp2f(m - tmax);
      l *= al;
#pragma unroll
      for (int f = 0; f < 4; f++) Oc[f] *= al;
      m = tmax;
    }
    float sum = 0.f;
#pragma unroll
    for (int kf = 0; kf < 4; kf++)
#pragma unroll
      for (int r = 0; r < 4; r++){
        float p = exp2f(sv[kf][r] - m);          // bounded by 2^11.5
        sv[kf][r] = p;
        sum += p;
      }
    sum += __shfl_xor(sum, 16, 64);
    sum += __shfl_xor(sum, 32, 64);
    l += sum;
    // ---- pack P -> LDS [q][k] stride 88 halves (conflict-free u32 writes / b128 reads)
#pragma unroll
    for (int kf = 0; kf < 4; kf++)
#pragma unroll
      for (int m2 = 0; m2 < 2; m2++){
        uint32_t u = (uint32_t)f2bf(sv[kf][2 * m2]) |
                     ((uint32_t)f2bf(sv[kf][2 * m2 + 1]) << 16);
        *(uint32_t*)(Pw + lrow * 88 + kf * 16 + 4 * lk + 2 * m2) = u;
      }
    // ---- PV: A = V^T rows (d), B = P^T cols (q) -> Oc(d_local, q)
#pragma unroll
    for (int ks = 0; ks < 2; ks++){
      s16x8 pB = *(const s16x8*)(Pw + lrow * 88 + ks * 32 + lk * 8);
#pragma unroll
      for (int f = 0; f < 4; f++)
        Oc[f] = mfma16(vreg[ks][f], pB, Oc[f]);
    }
  }
  // ---- epilogue: Out[q][b][h*64 + d],  d = f*16 + 4*lk + r
  float inv = 1.0f / l;
#pragma unroll
  for (int f = 0; f < 4; f++){
    f32x4 o = Oc[f] * inv;
    *(f32x4*)(Out + (size_t)(q0 + lrow) * 4096 + b * 1024 + h * 64 + f * 16 + 4 * lk) = o;
  }
}

extern "C" void kernel_launch(void* const* d_in, const int* in_sizes, int n_in,
                              void* d_out, int out_size, void* d_ws, size_t ws_size,
                              hipStream_t stream){
  const float* word = (const float*)d_in[0];   // [2048][4][1024]
  const float* pos  = (const float*)d_in[1];   // [2048][1024]
  const float* bq   = (const float*)d_in[2];   // [16][64]
  const float* bk   = (const float*)d_in[3];   // [16][64]
  const float* Wqkv = (const float*)d_in[4];   // [1024][3072]
  const float* Wr   = (const float*)d_in[5];   // [1024][1024]
  const float* br   = (const float*)d_in[6];   // [1024]
  float* out = (float*)d_out;

  char* ws = (char*)d_ws;
  size_t off = 0;
  u16* Abf   = (u16*)(ws + off); off += (size_t)8192 * 1024 * 2;
  u16* WqkvT = (u16*)(ws + off); off += (size_t)3072 * 1024 * 2;
  u16* Pbf   = (u16*)(ws + off); off += (size_t)2048 * 1024 * 2;
  u16* WrT   = (u16*)(ws + off); off += (size_t)1024 * 1024 * 2;
  u16* Qb    = (u16*)(ws + off); off += (size_t)64 * 2048 * 64 * 2;
  u16* Kb    = (u16*)(ws + off); off += (size_t)64 * 2048 * 64 * 2;
  u16* Vb    = (u16*)(ws + off); off += (size_t)64 * 2048 * 64 * 2;
  u16* VTb   = (u16*)(ws + off); off += (size_t)64 * 64 * 2048 * 2;
  u16* Rb    = (u16*)(ws + off); off += (size_t)16 * 2048 * 64 * 2;
  if (ws_size < off) return;

  cast_f32_bf16<<<4096, 256, 0, stream>>>(word, Abf, 1048576);
  cast_f32_bf16<<<1024, 256, 0, stream>>>(pos,  Pbf, 262144);
  tcast<<<dim3(96, 32), 256, 0, stream>>>(Wqkv, WqkvT, 1024, 3072);
  tcast<<<dim3(32, 32), 256, 0, stream>>>(Wr,   WrT,   1024, 1024);
  gemm_bt<<<dim3(24, 64), 256, 0, stream>>>(Abf, WqkvT, 0, Qb, Kb, Vb, nullptr, nullptr);
  gemm_bt<<<dim3(8, 16),  256, 0, stream>>>(Pbf, WrT,   1, nullptr, nullptr, nullptr, Rb, br);
  transpose_v<<<dim3(32, 64), 256, 0, stream>>>(Vb, VTb);
  attn2_kernel<<<dim3(32, 16, 4), 256, 0, stream>>>(Qb, Kb, VTb, Rb, bq, bk, out);
}

// Round 3
// 548.938 us; speedup vs baseline: 2.2426x; 1.8025x over previous
//
#include <hip/hip_runtime.h>
#include <stdint.h>

typedef unsigned short u16;
typedef __attribute__((ext_vector_type(8))) short  s16x8;
typedef __attribute__((ext_vector_type(8))) __bf16 b16x8;
typedef __attribute__((ext_vector_type(4))) float  f32x4;

__device__ __forceinline__ float bf2f(u16 u){
  union { unsigned int ui; float f; } v; v.ui = ((unsigned int)u) << 16; return v.f;
}
__device__ __forceinline__ u16 f2bf(float f){
  union { float f; unsigned int ui; } v; v.f = f;
  unsigned int u = v.ui;
  u += 0x7FFFu + ((u >> 16) & 1u);      // RNE
  return (u16)(u >> 16);
}
__device__ __forceinline__ f32x4 mfma16(s16x8 a, s16x8 b, f32x4 c){
  return __builtin_amdgcn_mfma_f32_16x16x32_bf16(
      __builtin_bit_cast(b16x8, a), __builtin_bit_cast(b16x8, b), c, 0, 0, 0);
}
// async global -> LDS, 16B per lane. lds ptr must be wave-uniform base; HW adds lane*16.
__device__ __forceinline__ void gload_lds16(const u16* g, u16* l){
  __builtin_amdgcn_global_load_lds(
      (const __attribute__((address_space(1))) unsigned int*)(g),
      (__attribute__((address_space(3))) unsigned int*)(l), 16, 0, 0);
}

// ---------------- elementwise cast f32 -> bf16 (8 elems/thread) ----------------
__global__ __launch_bounds__(256) void cast_f32_bf16(const float* __restrict__ in,
                                                     u16* __restrict__ out, int n8){
  int i = blockIdx.x * 256 + threadIdx.x;
  if (i >= n8) return;
  const f32x4* p = (const f32x4*)(in + (size_t)i * 8);
  f32x4 a = p[0], c = p[1];
  s16x8 o;
#pragma unroll
  for (int j = 0; j < 4; j++){ o[j] = (short)f2bf(a[j]); o[j+4] = (short)f2bf(c[j]); }
  *(s16x8*)(out + (size_t)i * 8) = o;
}

// ---------------- transpose + cast: in f32 [R][C] -> out bf16 [C][R] ----------------
__global__ __launch_bounds__(256) void tcast(const float* __restrict__ in,
                                             u16* __restrict__ out, int R, int C){
  __shared__ float tile[32][33];
  int c0 = blockIdx.x * 32, r0 = blockIdx.y * 32;
  int tc = threadIdx.x & 31, tr = threadIdx.x >> 5;
#pragma unroll
  for (int p = 0; p < 4; p++)
    tile[tr + 8*p][tc] = in[(size_t)(r0 + tr + 8*p) * C + c0 + tc];
  __syncthreads();
  int rr = threadIdx.x & 31, cc = threadIdx.x >> 5;
#pragma unroll
  for (int p = 0; p < 4; p++)
    out[(size_t)(c0 + cc + 8*p) * R + r0 + rr] = f2bf(tile[rr][cc + 8*p]);
}

// ---------------- GEMM: C[M,N] = A[M,K=1024] * Bt[N,K=1024]^T (bf16 MFMA) ----------------
__global__ __launch_bounds__(256) void gemm_bt(const u16* __restrict__ A,
                                               const u16* __restrict__ Bt,
                                               int mode,
                                               u16* __restrict__ Qo, u16* __restrict__ Ko,
                                               u16* __restrict__ Vo, u16* __restrict__ Ro,
                                               const float* __restrict__ brp){
  __shared__ __align__(16) u16 lsA[2][128 * 32];
  __shared__ __align__(16) u16 lsB[2][128 * 32];
  int m0 = blockIdx.y * 128, n0 = blockIdx.x * 128;
  int t = threadIdx.x, wid = t >> 6, lane = t & 63;
  int lrow = lane & 15, lk = lane >> 4;
  int wr = wid >> 1, wc = wid & 1;

  f32x4 acc[4][4];
#pragma unroll
  for (int i = 0; i < 4; i++)
#pragma unroll
    for (int j = 0; j < 4; j++) acc[i][j] = (f32x4){0.f, 0.f, 0.f, 0.f};

  const u16* Ab = A  + (size_t)m0 * 1024;
  const u16* Bb = Bt + (size_t)n0 * 1024;

  s16x8 ra[2], rb[2];
#pragma unroll
  for (int p = 0; p < 2; p++){
    int c = p * 256 + t;
    ra[p] = *(const s16x8*)(Ab + (size_t)(c >> 2) * 1024 + (c & 3) * 8);
    rb[p] = *(const s16x8*)(Bb + (size_t)(c >> 2) * 1024 + (c & 3) * 8);
  }

  for (int kt = 0; kt < 32; kt++){
    int buf = kt & 1;
#pragma unroll
    for (int p = 0; p < 2; p++){
      int c = p * 256 + t;
      *(s16x8*)(lsA[buf] + (size_t)c * 8) = ra[p];
      *(s16x8*)(lsB[buf] + (size_t)c * 8) = rb[p];
    }
    __syncthreads();
    if (kt < 31){
      int k0 = (kt + 1) * 32;
#pragma unroll
      for (int p = 0; p < 2; p++){
        int c = p * 256 + t;
        ra[p] = *(const s16x8*)(Ab + (size_t)(c >> 2) * 1024 + k0 + (c & 3) * 8);
        rb[p] = *(const s16x8*)(Bb + (size_t)(c >> 2) * 1024 + k0 + (c & 3) * 8);
      }
    }
    s16x8 af[4], bfr[4];
#pragma unroll
    for (int i = 0; i < 4; i++)
      af[i] = *(const s16x8*)(lsA[buf] + (wr * 64 + i * 16 + lrow) * 32 + lk * 8);
#pragma unroll
    for (int j = 0; j < 4; j++)
      bfr[j] = *(const s16x8*)(lsB[buf] + (wc * 64 + j * 16 + lrow) * 32 + lk * 8);
#pragma unroll
    for (int i = 0; i < 4; i++)
#pragma unroll
      for (int j = 0; j < 4; j++)
        acc[i][j] = mfma16(af[i], bfr[j], acc[i][j]);
    __syncthreads();
  }

#pragma unroll
  for (int i = 0; i < 4; i++)
#pragma unroll
    for (int j = 0; j < 4; j++){
      int mbase = m0 + wr * 64 + i * 16 + lk * 4;
      int ncol  = n0 + wc * 64 + j * 16 + lrow;
#pragma unroll
      for (int r = 0; r < 4; r++){
        int m = mbase + r;
        float val = acc[i][j][r];
        if (mode == 0){
          int sel = ncol >> 10;
          int hd = ncol & 1023;
          int h = hd >> 6, dh = hd & 63;
          int b = m & 3, iq = m >> 2;
          size_t o = ((size_t)(b * 16 + h) * 2048 + iq) * 64 + dh;
          u16 vb = f2bf(val);
          if (sel == 0) Qo[o] = vb; else if (sel == 1) Ko[o] = vb; else Vo[o] = vb;
        } else {
          int h = ncol >> 6, dh = ncol & 63;
          Ro[((size_t)h * 2048 + m) * 64 + dh] = f2bf(val + brp[ncol]);
        }
      }
    }
}

// ---------------- V [bh][2048][64] -> VT [bh][64][2048] (bf16) ----------------
__global__ __launch_bounds__(256) void transpose_v(const u16* __restrict__ V,
                                                   u16* __restrict__ VT){
  __shared__ u16 tile[64][65];
  int bh = blockIdx.y, i0 = blockIdx.x * 64;
  const u16* src = V + ((size_t)bh * 2048 + i0) * 64;
  int t = threadIdx.x;
#pragma unroll
  for (int p = 0; p < 2; p++){
    int idx = (p * 256 + t) * 8;
    int row = idx >> 6, col = idx & 63;
    s16x8 v = *(const s16x8*)(src + idx);
#pragma unroll
    for (int e = 0; e < 8; e++) tile[row][col + e] = (u16)v[e];
  }
  __syncthreads();
  u16* dst = VT + (size_t)bh * 64 * 2048 + i0;
#pragma unroll
  for (int p = 0; p < 2; p++){
    int idx = (p * 256 + t) * 8;
    int dh = idx >> 6, ii = idx & 63;
    s16x8 o;
#pragma unroll
    for (int e = 0; e < 8; e++) o[e] = (short)tile[ii + e][dh];
    *(s16x8*)(dst + (size_t)dh * 2048 + ii) = o;
  }
}

// ---------------- fused rel-shift flash attention v3 ----------------
// 1D grid 2048 (XCD-swizzled), 256 thr = 4 waves, wave = 16 q rows, KVBLK = 64.
// K/V tiles double-buffered in LDS (global_load_lds, XOR-swizzled chunk^=(row&7)).
// S^T = mfma(K, qa): q = lane&15 lane-local. BD via per-wave G LDS buffer (stride 84),
// P via same (union) buffer stride 88. One barrier per tile; stage t+1 issued early.
// BDs: d<=0 -> qb0 . r[d+2047]; d==1 -> 0; d>=2 -> qb1 . r[d-2]   (d = k - q)
__global__ __launch_bounds__(256) void attn3_kernel(const u16* __restrict__ Qm,
                                                    const u16* __restrict__ Km,
                                                    const u16* __restrict__ Vt,
                                                    const u16* __restrict__ Rm,
                                                    const float* __restrict__ bq,
                                                    const float* __restrict__ bk,
                                                    float* __restrict__ Out){
  __shared__ __align__(16) u16   Kt[2][64 * 64];
  __shared__ __align__(16) u16   Vs[2][64 * 64];
  __shared__ __align__(16) float Gs[4][16 * 84];   // per-wave; P aliases this

  // XCD-aware decode: 256 consecutive blocks (8 hb-groups x 32 q-tiles) per XCD
  int lin = blockIdx.x;
  int xcd = lin & 7, j = lin >> 3;
  int hb = xcd * 8 + (j >> 5);
  int bx = j & 31;
  int h = hb & 15, b = hb >> 4;

  const int wid = threadIdx.x >> 6, lane = threadIdx.x & 63;
  const int lrow = lane & 15, lk = lane >> 4;
  const int q0 = bx * 64 + wid * 16;
  const size_t bh = (size_t)b * 16 + h;
  const u16* Qp = Qm + bh * 2048 * 64;
  const u16* Kp = Km + bh * 2048 * 64;
  const u16* Vp = Vt + bh * 64 * 2048;
  const u16* Rp = Rm + (size_t)h * 2048 * 64;
  float* Gw = Gs[wid];
  u16*   Pw = (u16*)Gs[wid];

  // q fragments: frag[x=lane&15][k=(lane>>4)*8+j]
  s16x8 qa[2], qb0[2], qb1[2];
  {
    const float* bqp = bq + h * 64;
    const float* bkp = bk + h * 64;
    int r1 = q0 + lrow + 1; if (r1 > 2047) r1 = 2047;   // q=2047 shifted row never selected
#pragma unroll
    for (int d = 0; d < 2; d++){
      int doff = d * 32 + lk * 8;
      s16x8 raw  = *(const s16x8*)(Qp + (size_t)(q0 + lrow) * 64 + doff);
      s16x8 raw1 = *(const s16x8*)(Qp + (size_t)r1 * 64 + doff);
      s16x8 a, c0, c1;
#pragma unroll
      for (int jj = 0; jj < 8; jj++){
        float qv = bf2f((u16)raw[jj]);
        float q1 = bf2f((u16)raw1[jj]);
        a[jj]  = (short)f2bf(qv + bqp[doff + jj]);
        c0[jj] = (short)f2bf(qv + bkp[doff + jj]);
        c1[jj] = (short)f2bf(q1 + bkp[doff + jj]);
      }
      qa[d] = a; qb0[d] = c0; qb1[d] = c1;
    }
  }

  float m = -3.0e38f, l = 0.f;
  f32x4 Oc[4];
#pragma unroll
  for (int f = 0; f < 4; f++) Oc[f] = (f32x4){0.f, 0.f, 0.f, 0.f};

  const float cs = 0.125f * 1.44269504088896f;   // (1/sqrt(64)) * log2(e)
  const int wbase = 15 - lrow + 4 * lk;          // G gather base (kf=0, r=0)

  // ---- prologue: stage tile 0 into buf 0 (4 gload_lds per wave)
  {
#pragma unroll
    for (int i = 0; i < 2; i++){
      int g = wid * 2 + i;
      int row = g * 8 + (lane >> 3);
      int sch = (lane & 7) ^ (row & 7);
      gload_lds16(Kp + (size_t)row * 64 + sch * 8, Kt[0] + g * 512);
      gload_lds16(Vp + (size_t)row * 2048 + 0 + sch * 8, Vs[0] + g * 512);
    }
  }
  __syncthreads();

  for (int t = 0; t < 32; t++){
    const int k0 = t * 64;
    const int cur = t & 1;
    const int d0 = k0 - q0;
    const bool n1 = (d0 <= 15);
    const bool n2 = (d0 >= -61);

    // ---- R loads for first BD pass (issued before everything; latency hides under S)
    const int pb1 = n1 ? (d0 + 2032) : (d0 - 17);
    s16x8 rr[5][2];
#pragma unroll
    for (int wf = 0; wf < 5; wf++){
      int pr = pb1 + wf * 16 + lrow;
      pr = pr < 0 ? 0 : (pr > 2047 ? 2047 : pr);
#pragma unroll
      for (int d = 0; d < 2; d++)
        rr[wf][d] = *(const s16x8*)(Rp + (size_t)pr * 64 + d * 32 + lk * 8);
    }

    // ---- stage tile t+1 into other buffer (async; completes by end-of-tile barrier)
    if (t < 31){
      const u16* Kn = Kp + (size_t)(k0 + 64) * 64;
#pragma unroll
      for (int i = 0; i < 2; i++){
        int g = wid * 2 + i;
        int row = g * 8 + (lane >> 3);
        int sch = (lane & 7) ^ (row & 7);
        gload_lds16(Kn + (size_t)row * 64 + sch * 8, Kt[cur ^ 1] + g * 512);
        gload_lds16(Vp + (size_t)row * 2048 + (k0 + 64) + sch * 8, Vs[cur ^ 1] + g * 512);
      }
    }

    // ---- S^T = mfma(K, qa) from LDS (swizzled reads, conflict-free)
    f32x4 S[4];
#pragma unroll
    for (int kf = 0; kf < 4; kf++){
      f32x4 acc = (f32x4){0.f, 0.f, 0.f, 0.f};
#pragma unroll
      for (int d = 0; d < 2; d++){
        int row = kf * 16 + lrow;
        int ch = (d * 4 + lk) ^ (row & 7);
        s16x8 kfr = *(const s16x8*)(Kt[cur] + row * 64 + ch * 8);
        acc = mfma16(kfr, qa[d], acc);
      }
      S[kf] = acc;
    }

    const int dlane = d0 + 4 * lk - lrow;   // delta at (kf=0, r=0)

    // ---- BD first pass (rr already in flight)
    {
      const s16x8* qs = n1 ? qb0 : qb1;
#pragma unroll
      for (int wf = 0; wf < 5; wf++){
        f32x4 g = (f32x4){0.f, 0.f, 0.f, 0.f};
#pragma unroll
        for (int d = 0; d < 2; d++) g = mfma16(rr[wf][d], qs[d], g);
        *(f32x4*)(Gw + lrow * 84 + wf * 16 + 4 * lk) = g;
      }
      const float* gp = Gw + lrow * 84 + wbase;
      if (n1){
#pragma unroll
        for (int kf = 0; kf < 4; kf++)
#pragma unroll
          for (int r = 0; r < 4; r++){
            float g = gp[kf * 16 + r];
            S[kf][r] += (dlane + kf * 16 + r <= 0) ? g : 0.f;
          }
      } else {
#pragma unroll
        for (int kf = 0; kf < 4; kf++)
#pragma unroll
          for (int r = 0; r < 4; r++){
            float g = gp[kf * 16 + r];
            S[kf][r] += (dlane + kf * 16 + r >= 2) ? g : 0.f;
          }
      }
    }
    // ---- BD second pass (near-diagonal tiles only: ~2 of 32)
    if (n1 && n2){
      const int pb2 = d0 - 17;
#pragma unroll
      for (int wf = 0; wf < 5; wf++){
        int pr = pb2 + wf * 16 + lrow;
        pr = pr < 0 ? 0 : (pr > 2047 ? 2047 : pr);
#pragma unroll
        for (int d = 0; d < 2; d++)
          rr[wf][d] = *(const s16x8*)(Rp + (size_t)pr * 64 + d * 32 + lk * 8);
      }
#pragma unroll
      for (int wf = 0; wf < 5; wf++){
        f32x4 g = (f32x4){0.f, 0.f, 0.f, 0.f};
#pragma unroll
        for (int d = 0; d < 2; d++) g = mfma16(rr[wf][d], qb1[d], g);
        *(f32x4*)(Gw + lrow * 84 + wf * 16 + 4 * lk) = g;
      }
      const float* gp = Gw + lrow * 84 + wbase;
#pragma unroll
      for (int kf = 0; kf < 4; kf++)
#pragma unroll
        for (int r = 0; r < 4; r++){
          float g = gp[kf * 16 + r];
          S[kf][r] += (dlane + kf * 16 + r >= 2) ? g : 0.f;
        }
    }

    // ---- softmax (q lane-local, exp2 domain, defer-max)
    float tmax = -3.0e38f;
#pragma unroll
    for (int kf = 0; kf < 4; kf++)
#pragma unroll
      for (int r = 0; r < 4; r++){
        float s = S[kf][r] * cs;
        S[kf][r] = s;
        tmax = fmaxf(tmax, s);
      }
    tmax = fmaxf(tmax, __shfl_xor(tmax, 16, 64));
    tmax = fmaxf(tmax, __shfl_xor(tmax, 32, 64));
    if (tmax > m + 11.5f){
      float al = exp2f(m - tmax);
      l *= al;
#pragma unroll
      for (int f = 0; f < 4; f++) Oc[f] *= al;
      m = tmax;
    }
    float sum = 0.f;
#pragma unroll
    for (int kf = 0; kf < 4; kf++)
#pragma unroll
      for (int r = 0; r < 4; r++){
        float p = exp2f(S[kf][r] - m);
        S[kf][r] = p;
        sum += p;
      }
    sum += __shfl_xor(sum, 16, 64);
    sum += __shfl_xor(sum, 32, 64);
    l += sum;

    // ---- pack P -> LDS (aliases G; same-wave DS is in-order so no barrier needed)
#pragma unroll
    for (int kf = 0; kf < 4; kf++)
#pragma unroll
      for (int m2 = 0; m2 < 2; m2++){
        uint32_t u = (uint32_t)f2bf(S[kf][2 * m2]) |
                     ((uint32_t)f2bf(S[kf][2 * m2 + 1]) << 16);
        *(uint32_t*)(Pw + lrow * 88 + kf * 16 + 4 * lk + 2 * m2) = u;
      }
    // ---- PV: A = V^T rows (from LDS, swizzled), B = P^T
#pragma unroll
    for (int ks = 0; ks < 2; ks++){
      s16x8 pB = *(const s16x8*)(Pw + lrow * 88 + ks * 32 + lk * 8);
#pragma unroll
      for (int f = 0; f < 4; f++){
        int row = f * 16 + lrow;
        int ch = (ks * 4 + lk) ^ (row & 7);
        s16x8 vfr = *(const s16x8*)(Vs[cur] + row * 64 + ch * 8);
        Oc[f] = mfma16(vfr, pB, Oc[f]);
      }
    }
    __syncthreads();   // staging of t+1 complete; all waves done with cur
  }

  // ---- epilogue: Out[q][b][h*64 + d],  d = f*16 + 4*lk + r
  float inv = 1.0f / l;
#pragma unroll
  for (int f = 0; f < 4; f++){
    f32x4 o = Oc[f] * inv;
    *(f32x4*)(Out + (size_t)(q0 + lrow) * 4096 + b * 1024 + h * 64 + f * 16 + 4 * lk) = o;
  }
}

extern "C" void kernel_launch(void* const* d_in, const int* in_sizes, int n_in,
                              void* d_out, int out_size, void* d_ws, size_t ws_size,
                              hipStream_t stream){
  const float* word = (const float*)d_in[0];   // [2048][4][1024]
  const float* pos  = (const float*)d_in[1];   // [2048][1024]
  const float* bq   = (const float*)d_in[2];   // [16][64]
  const float* bk   = (const float*)d_in[3];   // [16][64]
  const float* Wqkv = (const float*)d_in[4];   // [1024][3072]
  const float* Wr   = (const float*)d_in[5];   // [1024][1024]
  const float* br   = (const float*)d_in[6];   // [1024]
  float* out = (float*)d_out;

  char* ws = (char*)d_ws;
  size_t off = 0;
  u16* Abf   = (u16*)(ws + off); off += (size_t)8192 * 1024 * 2;
  u16* WqkvT = (u16*)(ws + off); off += (size_t)3072 * 1024 * 2;
  u16* Pbf   = (u16*)(ws + off); off += (size_t)2048 * 1024 * 2;
  u16* WrT   = (u16*)(ws + off); off += (size_t)1024 * 1024 * 2;
  u16* Qb    = (u16*)(ws + off); off += (size_t)64 * 2048 * 64 * 2;
  u16* Kb    = (u16*)(ws + off); off += (size_t)64 * 2048 * 64 * 2;
  u16* Vb    = (u16*)(ws + off); off += (size_t)64 * 2048 * 64 * 2;
  u16* VTb   = (u16*)(ws + off); off += (size_t)64 * 64 * 2048 * 2;
  u16* Rb    = (u16*)(ws + off); off += (size_t)16 * 2048 * 64 * 2;
  if (ws_size < off) return;

  cast_f32_bf16<<<4096, 256, 0, stream>>>(word, Abf, 1048576);
  cast_f32_bf16<<<1024, 256, 0, stream>>>(pos,  Pbf, 262144);
  tcast<<<dim3(96, 32), 256, 0, stream>>>(Wqkv, WqkvT, 1024, 3072);
  tcast<<<dim3(32, 32), 256, 0, stream>>>(Wr,   WrT,   1024, 1024);
  gemm_bt<<<dim3(24, 64), 256, 0, stream>>>(Abf, WqkvT, 0, Qb, Kb, Vb, nullptr, nullptr);
  gemm_bt<<<dim3(8, 16),  256, 0, stream>>>(Pbf, WrT,   1, nullptr, nullptr, nullptr, Rb, br);
  transpose_v<<<dim3(32, 64), 256, 0, stream>>>(Vb, VTb);
  attn3_kernel<<<2048, 256, 0, stream>>>(Qb, Kb, VTb, Rb, bq, bk, out);
}